// Round 8
// baseline (102.391 us; speedup 1.0000x reference)
//
#include <hip/hip_runtime.h>

#define RB 10            // reachable bins: conf in (1/3, 1] -> bins 5..14
#define BIN_LO 5
#define GRID 2048
#define BLOCK 256
#define NWAVE (BLOCK / 64)
#define FBLOCK 1024      // final-reduce block

// Per-row contribution to bin(conf): x = conf - accuracy.
// ECE = sum_b |sum_{i in b} x_i| / N.
// Histogram: lane-private LDS columns h[bin][tid], accumulated with
// unsafeAtomicAdd -> native ds_add_f32 (fire-and-forget; R3/R4's slowness
// was safe-atomicAdd's CAS loop, not LDS itself).
__global__ __launch_bounds__(BLOCK) void ece_main(
    const float* __restrict__ logits,
    const int* __restrict__ labels,
    float* __restrict__ part,      // [RB][GRID] partials (or RB atomics)
    long long ngroups, long long nrows, int use_atomic)
{
    __shared__ float h[RB][BLOCK];
#pragma unroll
    for (int b = 0; b < RB; ++b) h[b][threadIdx.x] = 0.0f;
    __syncthreads();
    float* hcol = &h[0][threadIdx.x];   // column base; row stride = BLOCK

    auto proc = [&](float l0, float l1, float l2, int lab) {
        float m   = fmaxf(fmaxf(l0, l1), l2);          // v_max3_f32
        float mid = __builtin_amdgcn_fmed3f(l0, l1, l2);
        float lo  = fminf(fminf(l0, l1), l2);          // v_min3_f32
        // s = sum exp(l - m); the max term is exp(0)=1 exactly
        float s = 1.0f + __expf(mid - m) + __expf(lo - m);
        float conf = __builtin_amdgcn_rcpf(s);         // v_rcp_f32
        // accuracy: label's logit equals the max (tie flips <=2/N ECE)
        float ll = (lab == 1) ? l1 : l0;
        ll = (lab == 2) ? l2 : ll;
        float x = (ll == m) ? conf - 1.0f : conf;      // conf - acc
        // bin = floor(conf*15) in [5,14] -> idx in [0,9]; clamp for rcp slop
        int idx = (int)__builtin_fmaf(conf, 15.0f, (float)(-BIN_LO));
        idx = idx < 0 ? 0 : (idx > RB - 1 ? RB - 1 : idx);
        unsafeAtomicAdd(hcol + idx * BLOCK, x);        // ds_add_f32
    };

    const float4* __restrict__ L4  = (const float4*)logits;
    const int4*  __restrict__  Lb4 = (const int4*)labels;

    long long tid    = (long long)blockIdx.x * blockDim.x + threadIdx.x;
    long long stride = (long long)gridDim.x * blockDim.x;
#pragma unroll 2
    for (long long g = tid; g < ngroups; g += stride) {
        float4 a = L4[3 * g + 0];
        float4 b = L4[3 * g + 1];
        float4 c = L4[3 * g + 2];
        int4 lb  = Lb4[g];
        // rows: [a.x a.y a.z] [a.w b.x b.y] [b.z b.w c.x] [c.y c.z c.w]
        proc(a.x, a.y, a.z, lb.x);
        proc(a.w, b.x, b.y, lb.y);
        proc(b.z, b.w, c.x, lb.z);
        proc(c.y, c.z, c.w, lb.w);
    }
    // remainder rows (N % 4 != 0) — one thread, same private column
    if (tid == 0) {
        for (long long r = ngroups * 4; r < nrows; ++r)
            proc(logits[3 * r], logits[3 * r + 1], logits[3 * r + 2],
                 labels[r]);
    }

    __syncthreads();
    // reduce: each thread owns its column; shuffle across wave, then LDS
    float d[RB];
#pragma unroll
    for (int b = 0; b < RB; ++b) d[b] = h[b][threadIdx.x];
#pragma unroll
    for (int b = 0; b < RB; ++b)
#pragma unroll
        for (int off = 32; off > 0; off >>= 1)
            d[b] += __shfl_down(d[b], off, 64);

    __shared__ float sred[NWAVE][RB];
    int wave = threadIdx.x >> 6, lane = threadIdx.x & 63;
    if (lane == 0)
#pragma unroll
        for (int b = 0; b < RB; ++b) sred[wave][b] = d[b];
    __syncthreads();
    if (threadIdx.x < RB) {
        float v = sred[0][threadIdx.x] + sred[1][threadIdx.x] +
                  sred[2][threadIdx.x] + sred[3][threadIdx.x];
        if (use_atomic)
            atomicAdd(&part[threadIdx.x], v);
        else
            part[(long long)threadIdx.x * gridDim.x + blockIdx.x] = v;
    }
}

// Final: 1 block x 1024 threads; 2 coalesced loads per bin per thread.
__global__ __launch_bounds__(FBLOCK) void ece_final(
    const float* __restrict__ part, float* __restrict__ out,
    float invN, int use_atomic)
{
    if (use_atomic) {
        if (threadIdx.x == 0) {
            float e = 0.0f;
#pragma unroll
            for (int b = 0; b < RB; ++b) e += fabsf(part[b]);
            out[0] = e * invN;
        }
        return;
    }
    float v[RB];
#pragma unroll
    for (int b = 0; b < RB; ++b)
        v[b] = part[(long long)b * GRID + threadIdx.x] +
               part[(long long)b * GRID + FBLOCK + threadIdx.x];
#pragma unroll
    for (int b = 0; b < RB; ++b)
#pragma unroll
        for (int off = 32; off > 0; off >>= 1)
            v[b] += __shfl_down(v[b], off, 64);
    __shared__ float sred[FBLOCK / 64][RB];
    int wave = threadIdx.x >> 6, lane = threadIdx.x & 63;
    if (lane == 0)
#pragma unroll
        for (int b = 0; b < RB; ++b) sred[wave][b] = v[b];
    __syncthreads();
    if (threadIdx.x == 0) {
        float e = 0.0f;
#pragma unroll
        for (int b = 0; b < RB; ++b) {
            float t = 0.0f;
#pragma unroll
            for (int w = 0; w < FBLOCK / 64; ++w) t += sred[w][b];
            e += fabsf(t);
        }
        out[0] = e * invN;
    }
}

extern "C" void kernel_launch(void* const* d_in, const int* in_sizes, int n_in,
                              void* d_out, int out_size, void* d_ws, size_t ws_size,
                              hipStream_t stream) {
    const float* logits = (const float*)d_in[0];
    const int*   labels = (const int*)d_in[1];
    float* out  = (float*)d_out;
    float* ws   = (float*)d_ws;

    long long N = in_sizes[1];          // labels count = row count
    long long ngroups = N / 4;

    size_t need = (size_t)RB * GRID * sizeof(float);
    int use_atomic = (ws_size < need) ? 1 : 0;

    if (use_atomic)  // fallback path only: zero the 10-float accumulator
        hipMemsetAsync(ws, 0, RB * sizeof(float), stream);

    ece_main<<<GRID, BLOCK, 0, stream>>>(logits, labels, ws, ngroups, N,
                                         use_atomic);
    ece_final<<<1, FBLOCK, 0, stream>>>(ws, out, 1.0f / (float)N, use_atomic);
}

// Round 9
// 51.919 us; speedup vs baseline: 1.9721x; 1.9721x over previous
//
#include <hip/hip_runtime.h>

#define RB 10            // reachable bins: conf in (1/3, 1] -> bins 5..14
#define BIN_LO 5
#define GRID 2048
#define BLOCK 256
#define NWAVE (BLOCK / 64)
#define FBLOCK 1024      // final-reduce block

// Per-row contribution to bin(conf): x = conf - accuracy.
// ECE = sum_b |sum_{i in b} x_i| / N.
// Register predicated histogram (champion structure). This round: only
// proc_row changed vs R7 (clean A/B) — max3/med3/min3 softmax, label-
// select accuracy, RB 11->10. LDS histograms proven dead (R3/R4/R8).
__device__ __forceinline__ void proc_row(float l0, float l1, float l2, int lab,
                                         float* d) {
    float m   = fmaxf(fmaxf(l0, l1), l2);          // v_max3_f32
    float mid = __builtin_amdgcn_fmed3f(l0, l1, l2);
    float lo  = fminf(fminf(l0, l1), l2);          // v_min3_f32
    // s = sum exp(l - m); the max term is exp(0)=1 exactly
    float s = 1.0f + __expf(mid - m) + __expf(lo - m);
    float conf = __builtin_amdgcn_rcpf(s);         // v_rcp_f32
    // accuracy: label's logit equals the max (tie flips cost <=2/N in ECE)
    float ll = (lab == 1) ? l1 : l0;
    ll = (lab == 2) ? l2 : ll;
    float x = (ll == m) ? conf - 1.0f : conf;      // conf - acc
    // bin = floor(conf*15) in [5,14] -> idx in [0,9]; clamp for rcp slop
    int idx = (int)__builtin_fmaf(conf, 15.0f, (float)(-BIN_LO));
    idx = idx < 0 ? 0 : (idx > RB - 1 ? RB - 1 : idx);
#pragma unroll
    for (int b = 0; b < RB; ++b)
        d[b] += (idx == b) ? x : 0.0f;
}

__global__ __launch_bounds__(BLOCK) void ece_main(
    const float* __restrict__ logits,
    const int* __restrict__ labels,
    float* __restrict__ part,      // [RB][GRID] partials (or RB atomics)
    long long ngroups, long long nrows, int use_atomic)
{
    float d[RB];
#pragma unroll
    for (int b = 0; b < RB; ++b) d[b] = 0.0f;

    const float4* __restrict__ L4  = (const float4*)logits;
    const int4*  __restrict__  Lb4 = (const int4*)labels;

    long long tid    = (long long)blockIdx.x * blockDim.x + threadIdx.x;
    long long stride = (long long)gridDim.x * blockDim.x;
#pragma unroll 2
    for (long long g = tid; g < ngroups; g += stride) {
        float4 a = L4[3 * g + 0];
        float4 b = L4[3 * g + 1];
        float4 c = L4[3 * g + 2];
        int4 lb  = Lb4[g];
        // rows: [a.x a.y a.z] [a.w b.x b.y] [b.z b.w c.x] [c.y c.z c.w]
        proc_row(a.x, a.y, a.z, lb.x, d);
        proc_row(a.w, b.x, b.y, lb.y, d);
        proc_row(b.z, b.w, c.x, lb.z, d);
        proc_row(c.y, c.z, c.w, lb.w, d);
    }
    // remainder rows (N % 4 != 0) — one thread
    if (tid == 0) {
        for (long long r = ngroups * 4; r < nrows; ++r)
            proc_row(logits[3 * r], logits[3 * r + 1], logits[3 * r + 2],
                     labels[r], d);
    }

    // 64-lane shuffle reduction
#pragma unroll
    for (int b = 0; b < RB; ++b)
#pragma unroll
        for (int off = 32; off > 0; off >>= 1)
            d[b] += __shfl_down(d[b], off, 64);

    __shared__ float sred[NWAVE][RB];
    int wave = threadIdx.x >> 6, lane = threadIdx.x & 63;
    if (lane == 0)
#pragma unroll
        for (int b = 0; b < RB; ++b) sred[wave][b] = d[b];
    __syncthreads();
    if (threadIdx.x < RB) {
        float v = sred[0][threadIdx.x] + sred[1][threadIdx.x] +
                  sred[2][threadIdx.x] + sred[3][threadIdx.x];
        if (use_atomic)
            atomicAdd(&part[threadIdx.x], v);
        else
            part[(long long)threadIdx.x * gridDim.x + blockIdx.x] = v;
    }
}

// Final: 1 block x 1024 threads; 2 coalesced loads per bin per thread.
__global__ __launch_bounds__(FBLOCK) void ece_final(
    const float* __restrict__ part, float* __restrict__ out,
    float invN, int use_atomic)
{
    if (use_atomic) {
        if (threadIdx.x == 0) {
            float e = 0.0f;
#pragma unroll
            for (int b = 0; b < RB; ++b) e += fabsf(part[b]);
            out[0] = e * invN;
        }
        return;
    }
    float v[RB];
#pragma unroll
    for (int b = 0; b < RB; ++b)
        v[b] = part[(long long)b * GRID + threadIdx.x] +
               part[(long long)b * GRID + FBLOCK + threadIdx.x];
#pragma unroll
    for (int b = 0; b < RB; ++b)
#pragma unroll
        for (int off = 32; off > 0; off >>= 1)
            v[b] += __shfl_down(v[b], off, 64);
    __shared__ float sred[FBLOCK / 64][RB];
    int wave = threadIdx.x >> 6, lane = threadIdx.x & 63;
    if (lane == 0)
#pragma unroll
        for (int b = 0; b < RB; ++b) sred[wave][b] = v[b];
    __syncthreads();
    if (threadIdx.x == 0) {
        float e = 0.0f;
#pragma unroll
        for (int b = 0; b < RB; ++b) {
            float t = 0.0f;
#pragma unroll
            for (int w = 0; w < FBLOCK / 64; ++w) t += sred[w][b];
            e += fabsf(t);
        }
        out[0] = e * invN;
    }
}

extern "C" void kernel_launch(void* const* d_in, const int* in_sizes, int n_in,
                              void* d_out, int out_size, void* d_ws, size_t ws_size,
                              hipStream_t stream) {
    const float* logits = (const float*)d_in[0];
    const int*   labels = (const int*)d_in[1];
    float* out  = (float*)d_out;
    float* ws   = (float*)d_ws;

    long long N = in_sizes[1];          // labels count = row count
    long long ngroups = N / 4;

    size_t need = (size_t)RB * GRID * sizeof(float);
    int use_atomic = (ws_size < need) ? 1 : 0;

    if (use_atomic)  // fallback path only: zero the 10-float accumulator
        hipMemsetAsync(ws, 0, RB * sizeof(float), stream);

    ece_main<<<GRID, BLOCK, 0, stream>>>(logits, labels, ws, ngroups, N,
                                         use_atomic);
    ece_final<<<1, FBLOCK, 0, stream>>>(ws, out, 1.0f / (float)N, use_atomic);
}